// Round 1
// 362.578 us; speedup vs baseline: 1.0488x; 1.0488x over previous
//
#include <hip/hip_runtime.h>
#include <hip/hip_bf16.h>

typedef __hip_bfloat16 bf16;
typedef __attribute__((ext_vector_type(8))) short bf16x8;
typedef __attribute__((ext_vector_type(8))) unsigned short u16x8;
typedef __attribute__((ext_vector_type(4))) float f32x4;

__device__ __forceinline__ float b2f(unsigned short u) {
  return __uint_as_float(((unsigned)u) << 16);
}
__device__ __forceinline__ unsigned short f2b(float x) {
  bf16 h = __float2bfloat16(x);
  return *reinterpret_cast<unsigned short*>(&h);
}

// ============== passA: coarse hist of dst AND src + dtype probe ==============
// counts[0..M): dst buckets (counts[k*256+b]); counts[M..2M): src buckets.
__global__ void k_passA(const int* __restrict__ src, const int* __restrict__ dst, int E,
                        int nbuck, int M, int* __restrict__ counts,
                        const unsigned short* __restrict__ raw, int* __restrict__ flag) {
  if (blockIdx.x == 256) {
    __shared__ int sbad, snz;
    const int t = threadIdx.x;
    if (t == 0) { sbad = 0; snz = 0; }
    __syncthreads();
    const unsigned short u = raw[t];
    const float a = fabsf(b2f(u));
    if (!(a < 100.f)) atomicAdd(&sbad, 1);
    if (((t & 1) == 0) && u != 0) atomicAdd(&snz, 1);
    __syncthreads();
    if (t == 0) flag[0] = (sbad == 0 && snz > 0) ? 1 : 0;
    return;
  }
  extern __shared__ int lh[];  // lh1[nbuck] then lh2[nbuck]
  int* lh1 = lh;
  int* lh2 = lh + nbuck;
  const int t = threadIdx.x;
  for (int k = t; k < 2 * nbuck; k += 256) lh[k] = 0;
  __syncthreads();
  const int chunk = (E + 255) / 256;
  const int s = blockIdx.x * chunk;
  const int e = min(E, s + chunk);
  for (int i = s + t; i < e; i += 256) {
    atomicAdd(&lh1[dst[i] >> 8], 1);
    atomicAdd(&lh2[src[i] >> 8], 1);
  }
  __syncthreads();
  for (int k = t; k < nbuck; k += 256) {
    counts[k * 256 + blockIdx.x] = lh1[k];
    counts[M + k * 256 + blockIdx.x] = lh2[k];
  }
}

// exclusive scan over 2M ints
__global__ void k_scan1(const int* __restrict__ a, int M2, int* __restrict__ bsums) {
  __shared__ int sdata[256];
  int i = blockIdx.x * 256 + threadIdx.x;
  int v = (i < M2) ? a[i] : 0;
  sdata[threadIdx.x] = v;
  __syncthreads();
  for (int s = 128; s > 0; s >>= 1) {
    if (threadIdx.x < s) sdata[threadIdx.x] += sdata[threadIdx.x + s];
    __syncthreads();
  }
  if (threadIdx.x == 0) bsums[blockIdx.x] = sdata[0];
}

__global__ void k_scan2(int* __restrict__ bsums, int nb, int* __restrict__ rowStart,
                        int N, int E) {
  __shared__ int s[1024];
  const int t = threadIdx.x;
  const int v = (t < nb) ? bsums[t] : 0;
  s[t] = v;
  __syncthreads();
  for (int off = 1; off < 1024; off <<= 1) {
    int u = (t >= off) ? s[t - off] : 0;
    __syncthreads();
    s[t] += u;
    __syncthreads();
  }
  if (t < nb) bsums[t] = s[t] - v;  // exclusive
  if (t == 0) rowStart[N] = E;
}

__global__ void k_scan3(int* __restrict__ a, int M2, const int* __restrict__ bsums) {
  __shared__ int sdata[256];
  int i = blockIdx.x * 256 + threadIdx.x;
  int v = (i < M2) ? a[i] : 0;
  sdata[threadIdx.x] = v;
  __syncthreads();
  for (int off = 1; off < 256; off <<= 1) {
    int t = (threadIdx.x >= off) ? sdata[threadIdx.x - off] : 0;
    __syncthreads();
    sdata[threadIdx.x] += t;
    __syncthreads();
  }
  if (i < M2) a[i] = bsums[blockIdx.x] + sdata[threadIdx.x] - v;  // exclusive
}

// passC: dual scatter via LDS cursors — ZERO global atomics.
__global__ void k_passC(const int* __restrict__ src, const int* __restrict__ dst, int E,
                        int nbuck, int M, const int* __restrict__ S,
                        int* __restrict__ tmp, unsigned char* __restrict__ tmp2) {
  extern __shared__ int cur[];  // cur1[nbuck], cur2[nbuck]
  int* cur1 = cur;
  int* cur2 = cur + nbuck;
  const int t = threadIdx.x;
  for (int k = t; k < nbuck; k += 256) {
    cur1[k] = S[k * 256 + blockIdx.x];
    cur2[k] = S[M + k * 256 + blockIdx.x];
  }
  __syncthreads();
  const int chunk = (E + 255) / 256;
  const int s = blockIdx.x * chunk;
  const int e = min(E, s + chunk);
  for (int i = s + t; i < e; i += 256) {
    const int sv = src[i];
    const int d = dst[i];
    const int pos1 = atomicAdd(&cur1[d >> 8], 1);
    tmp[pos1] = sv | ((d & 255) << 20);
    const int pos2 = atomicAdd(&cur2[sv >> 8], 1);
    tmp2[pos2 - E] = (unsigned char)(sv & 255);
  }
}

// passD: per bucket k: (1) src-side byte hist -> deg_out -> ns;
//        (2) dst-side hist + scan -> rowStart, nd, edgeSrc scatter.
__global__ void k_passD(const int* __restrict__ tmp, const unsigned char* __restrict__ tmp2,
                        const int* __restrict__ S, int nbuck, int M, int N, int E,
                        int* __restrict__ rowStart, int* __restrict__ edgeSrc,
                        float* __restrict__ ns, float* __restrict__ nd) {
  __shared__ int h[256];
  __shared__ int ex[256];
  __shared__ int c[256];
  const int t = threadIdx.x;
  const int k = blockIdx.x;
  const int node = k * 256 + t;
  // ---- phase 1: src-side (deg_out -> ns) ----
  const int bs2 = S[M + k * 256] - E;
  const int be2 = (k + 1 < nbuck) ? (S[M + (k + 1) * 256] - E) : E;
  h[t] = 0;
  __syncthreads();
  for (int i = bs2 + t; i < be2; i += 256) atomicAdd(&h[tmp2[i]], 1);
  __syncthreads();
  if (node < N) {
    int dov = h[t];
    if (dov <= 0) dov = 1;
    ns[node] = rsqrtf((float)dov);
  }
  __syncthreads();
  // ---- phase 2: dst-side (rowStart, nd, edgeSrc) ----
  const int bs = S[k * 256];
  const int be = (k + 1 < nbuck) ? S[(k + 1) * 256] : E;
  h[t] = 0;
  __syncthreads();
  for (int i = bs + t; i < be; i += 256) atomicAdd(&h[tmp[i] >> 20], 1);
  __syncthreads();
  const int cnt = h[t];
  ex[t] = cnt;
  __syncthreads();
  for (int off = 1; off < 256; off <<= 1) {
    int u = (t >= off) ? ex[t - off] : 0;
    __syncthreads();
    ex[t] += u;
    __syncthreads();
  }
  const int excl = ex[t] - cnt;
  if (node < N) {
    rowStart[node] = bs + excl;
    nd[node] = rsqrtf((float)(cnt > 0 ? cnt : 1));
  }
  c[t] = bs + excl;
  __syncthreads();
  for (int i = bs + t; i < be; i += 256) {
    const int v = tmp[i];
    const int pos = atomicAdd(&c[v >> 20], 1);
    edgeSrc[pos] = v & 0xFFFFF;
  }
}

// ---------------- MFMA GEMM: out[r][c] = bf16( [ns[r]*] sum_k h[r][k]*W[k][c] ) ------
template <int K, bool FIRST, bool SCALE>
__global__ void k_gemm(const void* __restrict__ hin, const void* __restrict__ Wv,
                       const int* __restrict__ flag, const float* __restrict__ norm_src,
                       int N, unsigned short* __restrict__ out) {
  const bool isb = (*flag != 0);
  const int lane = threadIdx.x & 63;
  const int quad = lane >> 4;
  const int l16 = lane & 15;
  constexpr int KT = K / 32;

  bf16x8 Bf[KT][4];
  {
    const unsigned short* Wus = (const unsigned short*)Wv;
    const float* Wf = (const float*)Wv;
#pragma unroll
    for (int kt = 0; kt < KT; ++kt)
#pragma unroll
      for (int nt = 0; nt < 4; ++nt)
#pragma unroll
        for (int j = 0; j < 8; ++j) {
          const int k = kt * 32 + quad * 8 + j;
          const int n = nt * 16 + l16;
          const float w = isb ? b2f(Wus[k * 64 + n]) : Wf[k * 64 + n];
          Bf[kt][nt][j] = (short)f2b(w);
        }
  }
  const int wid = (blockIdx.x * blockDim.x + threadIdx.x) >> 6;
  const int nw = (gridDim.x * blockDim.x) >> 6;
  const int G = (N + 15) >> 4;
  for (int g = wid; g < G; g += nw) {
    int rowA = (g << 4) + l16;
    if (rowA >= N) rowA = N - 1;
    f32x4 acc[4] = {{0.f, 0.f, 0.f, 0.f}, {0.f, 0.f, 0.f, 0.f},
                    {0.f, 0.f, 0.f, 0.f}, {0.f, 0.f, 0.f, 0.f}};
#pragma unroll
    for (int kt = 0; kt < KT; ++kt) {
      const int koff = kt * 32 + quad * 8;
      bf16x8 Af;
      if (FIRST && !isb) {
        const float* hp = (const float*)hin + (size_t)rowA * K + koff;
        const float4 u0 = *(const float4*)hp;
        const float4 u1 = *(const float4*)(hp + 4);
        Af[0] = (short)f2b(u0.x); Af[1] = (short)f2b(u0.y);
        Af[2] = (short)f2b(u0.z); Af[3] = (short)f2b(u0.w);
        Af[4] = (short)f2b(u1.x); Af[5] = (short)f2b(u1.y);
        Af[6] = (short)f2b(u1.z); Af[7] = (short)f2b(u1.w);
      } else {
        Af = *(const bf16x8*)((const unsigned short*)hin + (size_t)rowA * K + koff);
      }
      acc[0] = __builtin_amdgcn_mfma_f32_16x16x32_bf16(Af, Bf[kt][0], acc[0], 0, 0, 0);
      acc[1] = __builtin_amdgcn_mfma_f32_16x16x32_bf16(Af, Bf[kt][1], acc[1], 0, 0, 0);
      acc[2] = __builtin_amdgcn_mfma_f32_16x16x32_bf16(Af, Bf[kt][2], acc[2], 0, 0, 0);
      acc[3] = __builtin_amdgcn_mfma_f32_16x16x32_bf16(Af, Bf[kt][3], acc[3], 0, 0, 0);
    }
    const int rowD = (g << 4) + quad * 4;
#pragma unroll
    for (int r = 0; r < 4; ++r) {
      if (rowD + r < N) {
        const float f = SCALE ? norm_src[rowD + r] : 1.0f;
        const size_t o = (size_t)(rowD + r) * 64 + l16;
#pragma unroll
        for (int nt = 0; nt < 4; ++nt)
          out[o + nt * 16] = f2b(SCALE ? acc[nt][r] * f : acc[nt][r]);
      }
    }
  }
}

// ---------------- aggregation: 4 nodes/wave, branch-free batched gathers -------------
// Latency-bound fix: per while-iteration issue ALL loads (8 idx dwords + 8 row
// gathers = 8 KB wave-level) in one basic block before any accumulate.
// lane = 8*eo + cg: eo = edge slot (0..7), cg = column group (8 bf16 cols).
template <bool LAST>
__global__ void k_aggregate(const unsigned short* __restrict__ proj,
                            const int* __restrict__ edgeSrc, const int* __restrict__ rowStart,
                            const float* __restrict__ norm_dst, const float* __restrict__ norm_src,
                            const void* __restrict__ bias, const int* __restrict__ flag,
                            int N, void* __restrict__ outp) {
  const bool isb = (*flag != 0);
  const int lane = threadIdx.x & 63;
  const int eo = lane >> 3;
  const int cg = lane & 7;
  float bcol[8];
#pragma unroll
  for (int j = 0; j < 8; ++j)
    bcol[j] = isb ? b2f(((const unsigned short*)bias)[cg * 8 + j])
                  : ((const float*)bias)[cg * 8 + j];
  const int wave = (blockIdx.x * blockDim.x + threadIdx.x) >> 6;
  const int nwaves = (gridDim.x * blockDim.x) >> 6;
  for (int n0 = wave * 4; n0 < N; n0 += nwaves * 4) {
    int base[4], cnt[4];
#pragma unroll
    for (int k = 0; k < 4; ++k) {
      const int lo = min(n0 + k, N);
      const int hi = min(n0 + k + 1, N);
      base[k] = rowStart[lo];
      cnt[k] = rowStart[hi] - base[k];
    }
    float a[4][8];
#pragma unroll
    for (int k = 0; k < 4; ++k)
#pragma unroll
      for (int j = 0; j < 8; ++j) a[k][j] = 0.f;
    int rem = cnt[0] + cnt[1] + cnt[2] + cnt[3];
    while (rem > 0) {
      // Per node: two 8-edge rounds (A: slots 0..7, B: slots 8..15).
      // Inactive slots read a clamped in-range address and contribute via
      // fmaf(x, 0, acc) — no divergent branches, so the compiler batches
      // all 16 loads ahead of the accumulates.
      int idxA[4], idxB[4], tk[4];
      float mA[4], mB[4];
#pragma unroll
      for (int k = 0; k < 4; ++k) {
        const int c = cnt[k];
        tk[k] = c < 16 ? c : 16;
        const bool aA = eo < c;
        const bool aB = (eo + 8) < tk[k];
        const int iA = edgeSrc[base[k] + (aA ? eo : 0)];
        const int iB = edgeSrc[base[k] + (aB ? eo + 8 : 0)];
        idxA[k] = aA ? iA : 0;   // clamp: garbage idx would be a wild gather
        idxB[k] = aB ? iB : 0;
        mA[k] = aA ? 1.f : 0.f;
        mB[k] = aB ? 1.f : 0.f;
      }
      u16x8 vA[4], vB[4];
#pragma unroll
      for (int k = 0; k < 4; ++k)
        vA[k] = *(const u16x8*)(proj + (size_t)idxA[k] * 64 + cg * 8);
#pragma unroll
      for (int k = 0; k < 4; ++k)
        vB[k] = *(const u16x8*)(proj + (size_t)idxB[k] * 64 + cg * 8);
#pragma unroll
      for (int k = 0; k < 4; ++k)
#pragma unroll
        for (int j = 0; j < 8; ++j)
          a[k][j] = fmaf(b2f((unsigned short)vA[k][j]), mA[k], a[k][j]);
#pragma unroll
      for (int k = 0; k < 4; ++k)
#pragma unroll
        for (int j = 0; j < 8; ++j)
          a[k][j] = fmaf(b2f((unsigned short)vB[k][j]), mB[k], a[k][j]);
      rem = 0;
#pragma unroll
      for (int k = 0; k < 4; ++k) {
        base[k] += tk[k];
        cnt[k] -= tk[k];
        rem += cnt[k];
      }
    }
    // reduce across the 8 edge slots (lanes differing in bits 3..5)
#pragma unroll
    for (int k = 0; k < 4; ++k)
#pragma unroll
      for (int j = 0; j < 8; ++j) {
        a[k][j] += __shfl_xor(a[k][j], 8, 64);
        a[k][j] += __shfl_xor(a[k][j], 16, 64);
        a[k][j] += __shfl_xor(a[k][j], 32, 64);
      }
    if (eo < 4) {
      const int n = n0 + eo;
      if (n < N) {
        const float nd = norm_dst[n];
        float r[8];
#pragma unroll
        for (int j = 0; j < 8; ++j) {
          const float av = (eo == 0) ? a[0][j]
                         : (eo == 1) ? a[1][j]
                         : (eo == 2) ? a[2][j] : a[3][j];
          r[j] = fmaxf(fmaf(av, nd, bcol[j]), 0.f);
        }
        if (!LAST) {
          const float esc = norm_src[n];
#pragma unroll
          for (int j = 0; j < 8; ++j) r[j] *= esc;
        }
        if (LAST && !isb) {
          float* of = (float*)outp + (size_t)n * 64 + cg * 8;
          float4 o0; o0.x = r[0]; o0.y = r[1]; o0.z = r[2]; o0.w = r[3];
          float4 o1; o1.x = r[4]; o1.y = r[5]; o1.z = r[6]; o1.w = r[7];
          *(float4*)of = o0;
          *(float4*)(of + 4) = o1;
        } else {
          u16x8 o;
#pragma unroll
          for (int j = 0; j < 8; ++j) o[j] = f2b(r[j]);
          *(u16x8*)((unsigned short*)outp + (size_t)n * 64 + cg * 8) = o;
        }
      }
    }
  }
}

extern "C" void kernel_launch(void* const* d_in, const int* in_sizes, int n_in,
                              void* d_out, int out_size, void* d_ws, size_t ws_size,
                              hipStream_t stream) {
  const void* features = d_in[0];
  const void* W0 = d_in[1];
  const void* b0 = d_in[2];
  const void* W1 = d_in[3];
  const void* b1 = d_in[4];
  const void* W2 = d_in[5];
  const void* b2 = d_in[6];
  const int* src = (const int*)d_in[7];
  const int* dst = (const int*)d_in[8];
  const int N = in_sizes[0] / 128;
  const int E = in_sizes[7];
  const int NBUCK = (N + 255) >> 8;  // 391
  const int M = NBUCK * 256;
  const int M2 = 2 * M;

  char* w = (char*)d_ws;
  size_t off = 0;
  auto alloc = [&](size_t bytes) {
    void* p = w + off;
    off = (off + bytes + 255) & ~(size_t)255;
    return p;
  };
  int* flag = (int*)alloc(4);
  int* rowStart = (int*)alloc((size_t)(N + 1) * 4);
  int* counts = (int*)alloc((size_t)M2 * 4);
  int* bsums = (int*)alloc(1024 * 4);
  float* norm_src = (float*)alloc((size_t)N * 4);
  float* norm_dst = (float*)alloc((size_t)N * 4);
  int* tmp = (int*)alloc((size_t)E * 4);
  unsigned char* tmp2 = (unsigned char*)alloc((size_t)E);
  int* edgeSrc = (int*)alloc((size_t)E * 4);
  unsigned short* projA = (unsigned short*)alloc((size_t)N * 64 * 2);  // bf16
  unsigned short* hB = (unsigned short*)d_out;  // inter-layer h (bf16) in d_out

  const size_t lds_nb = (size_t)NBUCK * 2 * 4;  // dual hist/cursors
  const int GB = ((N + 15) / 16 + 3) / 4;

  // CSR build — zero global atomics end-to-end, no memset needed.
  k_passA<<<257, 256, lds_nb, stream>>>(src, dst, E, NBUCK, M, counts,
                                        (const unsigned short*)features, flag);
  const int NB2 = (M2 + 255) / 256;  // == 2*NBUCK = 782
  k_scan1<<<NB2, 256, 0, stream>>>(counts, M2, bsums);
  k_scan2<<<1, 1024, 0, stream>>>(bsums, NB2, rowStart, N, E);
  k_scan3<<<NB2, 256, 0, stream>>>(counts, M2, bsums);
  k_passC<<<256, 256, lds_nb, stream>>>(src, dst, E, NBUCK, M, counts, tmp, tmp2);
  k_passD<<<NBUCK, 256, 0, stream>>>(tmp, tmp2, counts, NBUCK, M, N, E,
                                     rowStart, edgeSrc, norm_src, norm_dst);

  const int AB = (((N + 3) / 4) + 3) / 4;  // 4 nodes/wave, 4 waves/block
  // layer 0 (ns folded into gemm0 epilogue)
  k_gemm<128, true, true><<<GB, 256, 0, stream>>>(features, W0, flag, norm_src, N, projA);
  k_aggregate<false><<<AB, 256, 0, stream>>>(projA, edgeSrc, rowStart, norm_dst, norm_src, b0, flag, N, hB);
  // layer 1 (h pre-scaled by ns in agg epilogue)
  k_gemm<64, false, false><<<GB, 256, 0, stream>>>(hB, W1, flag, nullptr, N, projA);
  k_aggregate<false><<<AB, 256, 0, stream>>>(projA, edgeSrc, rowStart, norm_dst, norm_src, b1, flag, N, hB);
  // layer 2 -> d_out
  k_gemm<64, false, false><<<GB, 256, 0, stream>>>(hB, W2, flag, nullptr, N, projA);
  k_aggregate<true><<<AB, 256, 0, stream>>>(projA, edgeSrc, rowStart, norm_dst, norm_src, b2, flag, N, d_out);
}

// Round 2
// 339.311 us; speedup vs baseline: 1.1207x; 1.0686x over previous
//
#include <hip/hip_runtime.h>
#include <hip/hip_bf16.h>

typedef __hip_bfloat16 bf16;
typedef __attribute__((ext_vector_type(8))) short bf16x8;
typedef __attribute__((ext_vector_type(8))) unsigned short u16x8;
typedef __attribute__((ext_vector_type(4))) float f32x4;
typedef __attribute__((ext_vector_type(4))) int i32x4;
typedef __attribute__((ext_vector_type(4))) short s16x4;

__device__ __forceinline__ float b2f(unsigned short u) {
  return __uint_as_float(((unsigned)u) << 16);
}
__device__ __forceinline__ unsigned short f2b(float x) {
  bf16 h = __float2bfloat16(x);
  return *reinterpret_cast<unsigned short*>(&h);
}

// ============== passA: coarse hist of dst AND src + dtype probe ==============
__global__ void k_passA(const int* __restrict__ src, const int* __restrict__ dst, int E,
                        int nbuck, int M, int* __restrict__ counts,
                        const unsigned short* __restrict__ raw, int* __restrict__ flag) {
  if (blockIdx.x == 256) {
    __shared__ int sbad, snz;
    const int t = threadIdx.x;
    if (t == 0) { sbad = 0; snz = 0; }
    __syncthreads();
    const unsigned short u = raw[t];
    const float a = fabsf(b2f(u));
    if (!(a < 100.f)) atomicAdd(&sbad, 1);
    if (((t & 1) == 0) && u != 0) atomicAdd(&snz, 1);
    __syncthreads();
    if (t == 0) flag[0] = (sbad == 0 && snz > 0) ? 1 : 0;
    return;
  }
  extern __shared__ int lh[];
  int* lh1 = lh;
  int* lh2 = lh + nbuck;
  const int t = threadIdx.x;
  for (int k = t; k < 2 * nbuck; k += 256) lh[k] = 0;
  __syncthreads();
  const int chunk = (E + 255) / 256;
  const int s = blockIdx.x * chunk;
  const int e = min(E, s + chunk);
  for (int i = s + t; i < e; i += 256) {
    atomicAdd(&lh1[dst[i] >> 8], 1);
    atomicAdd(&lh2[src[i] >> 8], 1);
  }
  __syncthreads();
  for (int k = t; k < nbuck; k += 256) {
    counts[k * 256 + blockIdx.x] = lh1[k];
    counts[M + k * 256 + blockIdx.x] = lh2[k];
  }
}

__global__ void k_scan1(const int* __restrict__ a, int M2, int* __restrict__ bsums) {
  __shared__ int sdata[256];
  int i = blockIdx.x * 256 + threadIdx.x;
  int v = (i < M2) ? a[i] : 0;
  sdata[threadIdx.x] = v;
  __syncthreads();
  for (int s = 128; s > 0; s >>= 1) {
    if (threadIdx.x < s) sdata[threadIdx.x] += sdata[threadIdx.x + s];
    __syncthreads();
  }
  if (threadIdx.x == 0) bsums[blockIdx.x] = sdata[0];
}

__global__ void k_scan2(int* __restrict__ bsums, int nb, int* __restrict__ rowStart,
                        int N, int E) {
  __shared__ int s[1024];
  const int t = threadIdx.x;
  const int v = (t < nb) ? bsums[t] : 0;
  s[t] = v;
  __syncthreads();
  for (int off = 1; off < 1024; off <<= 1) {
    int u = (t >= off) ? s[t - off] : 0;
    __syncthreads();
    s[t] += u;
    __syncthreads();
  }
  if (t < nb) bsums[t] = s[t] - v;  // exclusive
  if (t == 0) rowStart[N] = E;
}

__global__ void k_scan3(int* __restrict__ a, int M2, const int* __restrict__ bsums) {
  __shared__ int sdata[256];
  int i = blockIdx.x * 256 + threadIdx.x;
  int v = (i < M2) ? a[i] : 0;
  sdata[threadIdx.x] = v;
  __syncthreads();
  for (int off = 1; off < 256; off <<= 1) {
    int t = (threadIdx.x >= off) ? sdata[threadIdx.x - off] : 0;
    __syncthreads();
    sdata[threadIdx.x] += t;
    __syncthreads();
  }
  if (i < M2) a[i] = bsums[blockIdx.x] + sdata[threadIdx.x] - v;  // exclusive
}

// passC: dual scatter via LDS cursors — ZERO global atomics.
__global__ void k_passC(const int* __restrict__ src, const int* __restrict__ dst, int E,
                        int nbuck, int M, const int* __restrict__ S,
                        int* __restrict__ tmp, unsigned char* __restrict__ tmp2) {
  extern __shared__ int cur[];
  int* cur1 = cur;
  int* cur2 = cur + nbuck;
  const int t = threadIdx.x;
  for (int k = t; k < nbuck; k += 256) {
    cur1[k] = S[k * 256 + blockIdx.x];
    cur2[k] = S[M + k * 256 + blockIdx.x];
  }
  __syncthreads();
  const int chunk = (E + 255) / 256;
  const int s = blockIdx.x * chunk;
  const int e = min(E, s + chunk);
  for (int i = s + t; i < e; i += 256) {
    const int sv = src[i];
    const int d = dst[i];
    const int pos1 = atomicAdd(&cur1[d >> 8], 1);
    tmp[pos1] = sv | ((d & 255) << 20);
    const int pos2 = atomicAdd(&cur2[sv >> 8], 1);
    tmp2[pos2 - E] = (unsigned char)(sv & 255);
  }
}

// passD: per bucket: src-side deg->ns; dst-side hist+scan -> rowStart, nd, edgeSrc.
__global__ void k_passD(const int* __restrict__ tmp, const unsigned char* __restrict__ tmp2,
                        const int* __restrict__ S, int nbuck, int M, int N, int E,
                        int* __restrict__ rowStart, int* __restrict__ edgeSrc,
                        float* __restrict__ ns, float* __restrict__ nd) {
  __shared__ int h[256];
  __shared__ int ex[256];
  __shared__ int c[256];
  const int t = threadIdx.x;
  const int k = blockIdx.x;
  const int node = k * 256 + t;
  const int bs2 = S[M + k * 256] - E;
  const int be2 = (k + 1 < nbuck) ? (S[M + (k + 1) * 256] - E) : E;
  h[t] = 0;
  __syncthreads();
  for (int i = bs2 + t; i < be2; i += 256) atomicAdd(&h[tmp2[i]], 1);
  __syncthreads();
  if (node < N) {
    int dov = h[t];
    if (dov <= 0) dov = 1;
    ns[node] = rsqrtf((float)dov);
  }
  __syncthreads();
  const int bs = S[k * 256];
  const int be = (k + 1 < nbuck) ? S[(k + 1) * 256] : E;
  h[t] = 0;
  __syncthreads();
  for (int i = bs + t; i < be; i += 256) atomicAdd(&h[tmp[i] >> 20], 1);
  __syncthreads();
  const int cnt = h[t];
  ex[t] = cnt;
  __syncthreads();
  for (int off = 1; off < 256; off <<= 1) {
    int u = (t >= off) ? ex[t - off] : 0;
    __syncthreads();
    ex[t] += u;
    __syncthreads();
  }
  const int excl = ex[t] - cnt;
  if (node < N) {
    rowStart[node] = bs + excl;
    nd[node] = rsqrtf((float)(cnt > 0 ? cnt : 1));
  }
  c[t] = bs + excl;
  __syncthreads();
  for (int i = bs + t; i < be; i += 256) {
    const int v = tmp[i];
    const int pos = atomicAdd(&c[v >> 20], 1);
    edgeSrc[pos] = v & 0xFFFFF;
  }
}

// ---------------- MFMA GEMM: out[r][c] = bf16( [ns[r]*] sum_k h[r][k]*W[k][c] ) ------
template <int K, bool FIRST, bool SCALE>
__global__ void k_gemm(const void* __restrict__ hin, const void* __restrict__ Wv,
                       const int* __restrict__ flag, const float* __restrict__ norm_src,
                       int N, unsigned short* __restrict__ out) {
  const bool isb = (*flag != 0);
  const int lane = threadIdx.x & 63;
  const int quad = lane >> 4;
  const int l16 = lane & 15;
  constexpr int KT = K / 32;

  bf16x8 Bf[KT][4];
  {
    const unsigned short* Wus = (const unsigned short*)Wv;
    const float* Wf = (const float*)Wv;
#pragma unroll
    for (int kt = 0; kt < KT; ++kt)
#pragma unroll
      for (int nt = 0; nt < 4; ++nt)
#pragma unroll
        for (int j = 0; j < 8; ++j) {
          const int k = kt * 32 + quad * 8 + j;
          const int n = nt * 16 + l16;
          const float w = isb ? b2f(Wus[k * 64 + n]) : Wf[k * 64 + n];
          Bf[kt][nt][j] = (short)f2b(w);
        }
  }
  const int wid = (blockIdx.x * blockDim.x + threadIdx.x) >> 6;
  const int nw = (gridDim.x * blockDim.x) >> 6;
  const int G = (N + 15) >> 4;
  for (int g = wid; g < G; g += nw) {
    int rowA = (g << 4) + l16;
    if (rowA >= N) rowA = N - 1;
    f32x4 acc[4] = {{0.f, 0.f, 0.f, 0.f}, {0.f, 0.f, 0.f, 0.f},
                    {0.f, 0.f, 0.f, 0.f}, {0.f, 0.f, 0.f, 0.f}};
#pragma unroll
    for (int kt = 0; kt < KT; ++kt) {
      const int koff = kt * 32 + quad * 8;
      bf16x8 Af;
      if (FIRST && !isb) {
        const float* hp = (const float*)hin + (size_t)rowA * K + koff;
        const float4 u0 = *(const float4*)hp;
        const float4 u1 = *(const float4*)(hp + 4);
        Af[0] = (short)f2b(u0.x); Af[1] = (short)f2b(u0.y);
        Af[2] = (short)f2b(u0.z); Af[3] = (short)f2b(u0.w);
        Af[4] = (short)f2b(u1.x); Af[5] = (short)f2b(u1.y);
        Af[6] = (short)f2b(u1.z); Af[7] = (short)f2b(u1.w);
      } else {
        Af = *(const bf16x8*)((const unsigned short*)hin + (size_t)rowA * K + koff);
      }
      acc[0] = __builtin_amdgcn_mfma_f32_16x16x32_bf16(Af, Bf[kt][0], acc[0], 0, 0, 0);
      acc[1] = __builtin_amdgcn_mfma_f32_16x16x32_bf16(Af, Bf[kt][1], acc[1], 0, 0, 0);
      acc[2] = __builtin_amdgcn_mfma_f32_16x16x32_bf16(Af, Bf[kt][2], acc[2], 0, 0, 0);
      acc[3] = __builtin_amdgcn_mfma_f32_16x16x32_bf16(Af, Bf[kt][3], acc[3], 0, 0, 0);
    }
    const int rowD = (g << 4) + quad * 4;
#pragma unroll
    for (int r = 0; r < 4; ++r) {
      if (rowD + r < N) {
        const float f = SCALE ? norm_src[rowD + r] : 1.0f;
        const size_t o = (size_t)(rowD + r) * 64 + l16;
#pragma unroll
        for (int nt = 0; nt < 4; ++nt)
          out[o + nt * 16] = f2b(SCALE ? acc[nt][r] * f : acc[nt][r]);
      }
    }
  }
}

// ---------------- MFMA aggregation (SpMM with segment-indicator A) -------------------
// Wave owns 8 consecutive dst nodes -> contiguous CSR edge segment. Chunks of 32
// edges: gather 32 proj rows -> per-wave LDS tile [k=32][n=64] (4 regions of
// [32][16], n-fastest), read B-fragments via ds_read_b64_tr_b16, A = 0/1 segment
// indicator (in tr-read k-order), D accumulated via mfma 16x16x32_bf16.
// MFMA k-slot (quad,j) <-> edge offset E(quad,j) = quad*4+j (j<4) else 16+quad*4+j-4.
__device__ __forceinline__ void agg_chunk_compute(unsigned trbase, int cb32, int lo,
                                                  unsigned span, int quad, f32x4* acc) {
  // A-indicator fragment (rows = l16 handled implicitly: lo/span are per-lane)
  const int posbase = cb32 + (quad << 2);
  const unsigned u0 = (unsigned)(posbase - lo);
  bf16x8 Af;
#pragma unroll
  for (int j = 0; j < 8; ++j) {
    const unsigned off = (j < 4) ? (unsigned)j : (unsigned)(12 + j);
    Af[j] = ((u0 + off) < span) ? (short)0x3F80 : (short)0;
  }
  s16x4 t0[4], t1[4];
#pragma unroll
  for (int nt = 0; nt < 4; ++nt) {
    const unsigned a = trbase + (unsigned)(nt * 1024);
    asm volatile("ds_read_b64_tr_b16 %0, %1" : "=v"(t0[nt]) : "v"(a) : "memory");
    asm volatile("ds_read_b64_tr_b16 %0, %1 offset:512" : "=v"(t1[nt]) : "v"(a) : "memory");
  }
  asm volatile("s_waitcnt lgkmcnt(0)" ::: "memory");
  __builtin_amdgcn_sched_barrier(0);
#pragma unroll
  for (int nt = 0; nt < 4; ++nt) {
    bf16x8 Bf;
    Bf[0] = t0[nt][0]; Bf[1] = t0[nt][1]; Bf[2] = t0[nt][2]; Bf[3] = t0[nt][3];
    Bf[4] = t1[nt][0]; Bf[5] = t1[nt][1]; Bf[6] = t1[nt][2]; Bf[7] = t1[nt][3];
    acc[nt] = __builtin_amdgcn_mfma_f32_16x16x32_bf16(Af, Bf, acc[nt], 0, 0, 0);
  }
}

template <bool LAST>
__global__ void __launch_bounds__(256) k_aggregate(
    const unsigned short* __restrict__ proj,
    const int* __restrict__ edgeSrc, const int* __restrict__ rowStart,
    const float* __restrict__ norm_dst, const float* __restrict__ norm_src,
    const void* __restrict__ bias, const int* __restrict__ flag,
    int N, int E, void* __restrict__ outp) {
  __shared__ unsigned short lds[4][2048];  // 4 KB per wave: [32 edges][64 cols]
  const bool isb = (*flag != 0);
  const int tid = threadIdx.x;
  const int w = tid >> 6;
  const int lane = tid & 63;
  const int l16 = lane & 15;
  const int quad = lane >> 4;
  const int e32 = lane & 31;  // edge slot within chunk
  const int p = lane >> 5;    // 64-byte half of the 128-byte row

  const int wid = blockIdx.x * 4 + w;
  const int g0 = wid * 8;

  float bcol[4];
#pragma unroll
  for (int nt = 0; nt < 4; ++nt) {
    const int col = nt * 16 + l16;
    bcol[nt] = isb ? b2f(((const unsigned short*)bias)[col]) : ((const float*)bias)[col];
  }

  const int cb = rowStart[min(g0, N)];
  const int ce = rowStart[min(g0 + 8, N)];
  const int L = ce - cb;
  const int nch = (L + 31) >> 5;

  // per-lane node interval (row r = l16; rows >= 8 empty)
  const int rsi = min(g0 + min(l16, 8), N);
  const int rsj = min(g0 + min(l16 + 1, 8), N);
  const int lo = rowStart[rsi];
  const unsigned span = (unsigned)(rowStart[rsj] - lo);

  // upfront edge-index loads for up to 6 chunks (L <= 192 covers ~all waves)
  int idxc[6];
#pragma unroll
  for (int t = 0; t < 6; ++t) {
    const int pos = min(cb + t * 32 + e32, E - 1);
    idxc[t] = edgeSrc[pos];
  }

  // LDS staging offsets (in shorts): element (k=e32, n) at nt*512 + e32*16 + (n&15)
  unsigned short* myl = &lds[w][0];
  unsigned wofs[4];
#pragma unroll
  for (int q = 0; q < 4; ++q) {
    const int n0 = p * 32 + q * 8;
    wofs[q] = (unsigned)((n0 >> 4) * 512 + e32 * 16 + (n0 & 15));
  }
  const unsigned trbase = (unsigned)(uintptr_t)myl + (unsigned)lane * 8u;

  f32x4 acc[4] = {{0.f, 0.f, 0.f, 0.f}, {0.f, 0.f, 0.f, 0.f},
                  {0.f, 0.f, 0.f, 0.f}, {0.f, 0.f, 0.f, 0.f}};

  i32x4 gb[2][4];
#define AGG_ISSUE(t, b)                                                         \
  {                                                                             \
    const unsigned short* rp = proj + (size_t)idxc[t] * 64 + p * 32;            \
    gb[b][0] = *(const i32x4*)(rp);                                             \
    gb[b][1] = *(const i32x4*)(rp + 8);                                         \
    gb[b][2] = *(const i32x4*)(rp + 16);                                        \
    gb[b][3] = *(const i32x4*)(rp + 24);                                        \
  }
  if (0 < nch) AGG_ISSUE(0, 0);
  if (1 < nch) AGG_ISSUE(1, 1);

#pragma unroll
  for (int tt = 0; tt < 6; ++tt) {
    if (tt < nch) {
      // stage chunk tt into this wave's LDS tile
#pragma unroll
      for (int q = 0; q < 4; ++q) *(i32x4*)(myl + wofs[q]) = gb[tt & 1][q];
      // prefetch chunk tt+2 into the freed buffer
      if (tt + 2 < 6 && tt + 2 < nch) AGG_ISSUE(tt + 2, tt & 1);
      asm volatile("s_waitcnt lgkmcnt(0)" ::: "memory");
      agg_chunk_compute(trbase, cb + tt * 32, lo, span, quad, acc);
    }
  }
  // cold tail (essentially never for Poisson(16) degrees: L > 192)
  for (int t = 6; t < nch; ++t) {
    const int pos = min(cb + t * 32 + e32, E - 1);
    const int idx = edgeSrc[pos];
    const unsigned short* rp = proj + (size_t)idx * 64 + p * 32;
    i32x4 g4[4];
    g4[0] = *(const i32x4*)(rp);
    g4[1] = *(const i32x4*)(rp + 8);
    g4[2] = *(const i32x4*)(rp + 16);
    g4[3] = *(const i32x4*)(rp + 24);
#pragma unroll
    for (int q = 0; q < 4; ++q) *(i32x4*)(myl + wofs[q]) = g4[q];
    asm volatile("s_waitcnt lgkmcnt(0)" ::: "memory");
    agg_chunk_compute(trbase, cb + t * 32, lo, span, quad, acc);
  }
#undef AGG_ISSUE

  // epilogue: D rows r = quad*4 + reg (valid r < 8), col = nt*16 + l16
#pragma unroll
  for (int reg = 0; reg < 4; ++reg) {
    const int row = quad * 4 + reg;
    const int node = g0 + row;
    if (row < 8 && node < N) {
      const float nd = norm_dst[node];
      const float esc = LAST ? 1.f : norm_src[node];
#pragma unroll
      for (int nt = 0; nt < 4; ++nt) {
        float x = fmaxf(fmaf(acc[nt][reg], nd, bcol[nt]), 0.f);
        if (!LAST) x *= esc;
        const size_t o = (size_t)node * 64 + nt * 16 + l16;
        if (LAST && !isb)
          ((float*)outp)[o] = x;
        else
          ((unsigned short*)outp)[o] = f2b(x);
      }
    }
  }
}

extern "C" void kernel_launch(void* const* d_in, const int* in_sizes, int n_in,
                              void* d_out, int out_size, void* d_ws, size_t ws_size,
                              hipStream_t stream) {
  const void* features = d_in[0];
  const void* W0 = d_in[1];
  const void* b0 = d_in[2];
  const void* W1 = d_in[3];
  const void* b1 = d_in[4];
  const void* W2 = d_in[5];
  const void* b2 = d_in[6];
  const int* src = (const int*)d_in[7];
  const int* dst = (const int*)d_in[8];
  const int N = in_sizes[0] / 128;
  const int E = in_sizes[7];
  const int NBUCK = (N + 255) >> 8;
  const int M = NBUCK * 256;
  const int M2 = 2 * M;

  char* w = (char*)d_ws;
  size_t off = 0;
  auto alloc = [&](size_t bytes) {
    void* p = w + off;
    off = (off + bytes + 255) & ~(size_t)255;
    return p;
  };
  int* flag = (int*)alloc(4);
  int* rowStart = (int*)alloc((size_t)(N + 1) * 4);
  int* counts = (int*)alloc((size_t)M2 * 4);
  int* bsums = (int*)alloc(1024 * 4);
  float* norm_src = (float*)alloc((size_t)N * 4);
  float* norm_dst = (float*)alloc((size_t)N * 4);
  int* tmp = (int*)alloc((size_t)E * 4);
  unsigned char* tmp2 = (unsigned char*)alloc((size_t)E);
  int* edgeSrc = (int*)alloc((size_t)E * 4);
  unsigned short* projA = (unsigned short*)alloc((size_t)N * 64 * 2);  // bf16
  unsigned short* hB = (unsigned short*)d_out;  // inter-layer h (bf16) in d_out

  const size_t lds_nb = (size_t)NBUCK * 2 * 4;
  const int GB = ((N + 15) / 16 + 3) / 4;

  // CSR build — zero global atomics end-to-end, no memset needed.
  k_passA<<<257, 256, lds_nb, stream>>>(src, dst, E, NBUCK, M, counts,
                                        (const unsigned short*)features, flag);
  const int NB2 = (M2 + 255) / 256;
  k_scan1<<<NB2, 256, 0, stream>>>(counts, M2, bsums);
  k_scan2<<<1, 1024, 0, stream>>>(bsums, NB2, rowStart, N, E);
  k_scan3<<<NB2, 256, 0, stream>>>(counts, M2, bsums);
  k_passC<<<256, 256, lds_nb, stream>>>(src, dst, E, NBUCK, M, counts, tmp, tmp2);
  k_passD<<<NBUCK, 256, 0, stream>>>(tmp, tmp2, counts, NBUCK, M, N, E,
                                     rowStart, edgeSrc, norm_src, norm_dst);

  const int AB = (((N + 7) / 8) + 3) / 4;  // 8 nodes/wave, 4 waves/block
  // layer 0 (ns folded into gemm0 epilogue)
  k_gemm<128, true, true><<<GB, 256, 0, stream>>>(features, W0, flag, norm_src, N, projA);
  k_aggregate<false><<<AB, 256, 0, stream>>>(projA, edgeSrc, rowStart, norm_dst, norm_src, b0, flag, N, E, hB);
  // layer 1 (h pre-scaled by ns in agg epilogue)
  k_gemm<64, false, false><<<GB, 256, 0, stream>>>(hB, W1, flag, nullptr, N, projA);
  k_aggregate<false><<<AB, 256, 0, stream>>>(projA, edgeSrc, rowStart, norm_dst, norm_src, b1, flag, N, E, hB);
  // layer 2 -> d_out
  k_gemm<64, false, false><<<GB, 256, 0, stream>>>(hB, W2, flag, nullptr, N, projA);
  k_aggregate<true><<<AB, 256, 0, stream>>>(projA, edgeSrc, rowStart, norm_dst, norm_src, b2, flag, N, E, d_out);
}

// Round 3
// 311.979 us; speedup vs baseline: 1.2189x; 1.0876x over previous
//
#include <hip/hip_runtime.h>
#include <hip/hip_bf16.h>

typedef __hip_bfloat16 bf16;
typedef __attribute__((ext_vector_type(8))) short bf16x8;
typedef __attribute__((ext_vector_type(8))) unsigned short u16x8;
typedef __attribute__((ext_vector_type(4))) float f32x4;
typedef __attribute__((ext_vector_type(4))) int i32x4;
typedef __attribute__((ext_vector_type(4))) short s16x4;

__device__ __forceinline__ float b2f(unsigned short u) {
  return __uint_as_float(((unsigned)u) << 16);
}
__device__ __forceinline__ unsigned short f2b(float x) {
  bf16 h = __float2bfloat16(x);
  return *reinterpret_cast<unsigned short*>(&h);
}

// ============== passA: coarse hist of dst AND src + dtype probe ==============
__global__ void k_passA(const int* __restrict__ src, const int* __restrict__ dst, int E,
                        int nbuck, int M, int* __restrict__ counts,
                        const unsigned short* __restrict__ raw, int* __restrict__ flag) {
  if (blockIdx.x == 256) {
    __shared__ int sbad, snz;
    const int t = threadIdx.x;
    if (t == 0) { sbad = 0; snz = 0; }
    __syncthreads();
    const unsigned short u = raw[t];
    const float a = fabsf(b2f(u));
    if (!(a < 100.f)) atomicAdd(&sbad, 1);
    if (((t & 1) == 0) && u != 0) atomicAdd(&snz, 1);
    __syncthreads();
    if (t == 0) flag[0] = (sbad == 0 && snz > 0) ? 1 : 0;
    return;
  }
  extern __shared__ int lh[];
  int* lh1 = lh;
  int* lh2 = lh + nbuck;
  const int t = threadIdx.x;
  for (int k = t; k < 2 * nbuck; k += 256) lh[k] = 0;
  __syncthreads();
  const int chunk = (E + 255) / 256;
  const int s = blockIdx.x * chunk;
  const int e = min(E, s + chunk);
  for (int i = s + t; i < e; i += 256) {
    atomicAdd(&lh1[dst[i] >> 8], 1);
    atomicAdd(&lh2[src[i] >> 8], 1);
  }
  __syncthreads();
  for (int k = t; k < nbuck; k += 256) {
    counts[k * 256 + blockIdx.x] = lh1[k];
    counts[M + k * 256 + blockIdx.x] = lh2[k];
  }
}

__global__ void k_scan1(const int* __restrict__ a, int M2, int* __restrict__ bsums) {
  __shared__ int sdata[256];
  int i = blockIdx.x * 256 + threadIdx.x;
  int v = (i < M2) ? a[i] : 0;
  sdata[threadIdx.x] = v;
  __syncthreads();
  for (int s = 128; s > 0; s >>= 1) {
    if (threadIdx.x < s) sdata[threadIdx.x] += sdata[threadIdx.x + s];
    __syncthreads();
  }
  if (threadIdx.x == 0) bsums[blockIdx.x] = sdata[0];
}

__global__ void k_scan2(int* __restrict__ bsums, int nb, int* __restrict__ rowStart,
                        int N, int E) {
  __shared__ int s[1024];
  const int t = threadIdx.x;
  const int v = (t < nb) ? bsums[t] : 0;
  s[t] = v;
  __syncthreads();
  for (int off = 1; off < 1024; off <<= 1) {
    int u = (t >= off) ? s[t - off] : 0;
    __syncthreads();
    s[t] += u;
    __syncthreads();
  }
  if (t < nb) bsums[t] = s[t] - v;  // exclusive
  if (t == 0) rowStart[N] = E;
}

__global__ void k_scan3(int* __restrict__ a, int M2, const int* __restrict__ bsums) {
  __shared__ int sdata[256];
  int i = blockIdx.x * 256 + threadIdx.x;
  int v = (i < M2) ? a[i] : 0;
  sdata[threadIdx.x] = v;
  __syncthreads();
  for (int off = 1; off < 256; off <<= 1) {
    int t = (threadIdx.x >= off) ? sdata[threadIdx.x - off] : 0;
    __syncthreads();
    sdata[threadIdx.x] += t;
    __syncthreads();
  }
  if (i < M2) a[i] = bsums[blockIdx.x] + sdata[threadIdx.x] - v;  // exclusive
}

// passC: dual scatter via LDS cursors — ZERO global atomics.
__global__ void k_passC(const int* __restrict__ src, const int* __restrict__ dst, int E,
                        int nbuck, int M, const int* __restrict__ S,
                        int* __restrict__ tmp, unsigned char* __restrict__ tmp2) {
  extern __shared__ int cur[];
  int* cur1 = cur;
  int* cur2 = cur + nbuck;
  const int t = threadIdx.x;
  for (int k = t; k < nbuck; k += 256) {
    cur1[k] = S[k * 256 + blockIdx.x];
    cur2[k] = S[M + k * 256 + blockIdx.x];
  }
  __syncthreads();
  const int chunk = (E + 255) / 256;
  const int s = blockIdx.x * chunk;
  const int e = min(E, s + chunk);
  for (int i = s + t; i < e; i += 256) {
    const int sv = src[i];
    const int d = dst[i];
    const int pos1 = atomicAdd(&cur1[d >> 8], 1);
    tmp[pos1] = sv | ((d & 255) << 20);
    const int pos2 = atomicAdd(&cur2[sv >> 8], 1);
    tmp2[pos2 - E] = (unsigned char)(sv & 255);
  }
}

// passD: per bucket: src-side deg->ns; dst-side hist+scan -> rowStart, nd, edgeSrc.
__global__ void k_passD(const int* __restrict__ tmp, const unsigned char* __restrict__ tmp2,
                        const int* __restrict__ S, int nbuck, int M, int N, int E,
                        int* __restrict__ rowStart, int* __restrict__ edgeSrc,
                        float* __restrict__ ns, float* __restrict__ nd) {
  __shared__ int h[256];
  __shared__ int ex[256];
  __shared__ int c[256];
  const int t = threadIdx.x;
  const int k = blockIdx.x;
  const int node = k * 256 + t;
  const int bs2 = S[M + k * 256] - E;
  const int be2 = (k + 1 < nbuck) ? (S[M + (k + 1) * 256] - E) : E;
  h[t] = 0;
  __syncthreads();
  for (int i = bs2 + t; i < be2; i += 256) atomicAdd(&h[tmp2[i]], 1);
  __syncthreads();
  if (node < N) {
    int dov = h[t];
    if (dov <= 0) dov = 1;
    ns[node] = rsqrtf((float)dov);
  }
  __syncthreads();
  const int bs = S[k * 256];
  const int be = (k + 1 < nbuck) ? S[(k + 1) * 256] : E;
  h[t] = 0;
  __syncthreads();
  for (int i = bs + t; i < be; i += 256) atomicAdd(&h[tmp[i] >> 20], 1);
  __syncthreads();
  const int cnt = h[t];
  ex[t] = cnt;
  __syncthreads();
  for (int off = 1; off < 256; off <<= 1) {
    int u = (t >= off) ? ex[t - off] : 0;
    __syncthreads();
    ex[t] += u;
    __syncthreads();
  }
  const int excl = ex[t] - cnt;
  if (node < N) {
    rowStart[node] = bs + excl;
    nd[node] = rsqrtf((float)(cnt > 0 ? cnt : 1));
  }
  c[t] = bs + excl;
  __syncthreads();
  for (int i = bs + t; i < be; i += 256) {
    const int v = tmp[i];
    const int pos = atomicAdd(&c[v >> 20], 1);
    edgeSrc[pos] = v & 0xFFFFF;
  }
}

// ---------------- MFMA GEMM (LDS-staged W + vectorized C-write) ----------------------
// W staged ONCE per block into LDS, transposed [n][K] (stride K+8 shorts) so each
// lane's B-fragment is one contiguous ds_read_b128. C transposed through a per-wave
// LDS tile -> dwordx4 coalesced stores (kills write-allocate RMW of 2B stores).
template <int K, bool FIRST, bool SCALE>
__global__ void __launch_bounds__(256) k_gemm(
    const void* __restrict__ hin, const void* __restrict__ Wv,
    const int* __restrict__ flag, const float* __restrict__ norm_src,
    int N, unsigned short* __restrict__ out) {
  constexpr int ST = K + 8;     // W-tile row stride (shorts)
  constexpr int CST = 72;       // C-tile row stride (shorts)
  __shared__ unsigned short Wl[64 * ST];
  __shared__ unsigned short Cl[4][16 * CST];
  const bool isb = (*flag != 0);
  const int tid = threadIdx.x;

  // ---- stage W once per block: W[k][n] -> Wl[n][k] (bf16) ----
  {
    const unsigned short* Wus = (const unsigned short*)Wv;
    const float* Wf = (const float*)Wv;
    for (int i0 = tid * 8; i0 < K * 64; i0 += 2048) {
      const int k = i0 >> 6;
      const int n0 = i0 & 63;
      unsigned short v[8];
      if (isb) {
        const u16x8 u = *(const u16x8*)(Wus + i0);
#pragma unroll
        for (int j = 0; j < 8; ++j) v[j] = u[j];
      } else {
        const float4 f0 = *(const float4*)(Wf + i0);
        const float4 f1 = *(const float4*)(Wf + i0 + 4);
        v[0] = f2b(f0.x); v[1] = f2b(f0.y); v[2] = f2b(f0.z); v[3] = f2b(f0.w);
        v[4] = f2b(f1.x); v[5] = f2b(f1.y); v[6] = f2b(f1.z); v[7] = f2b(f1.w);
      }
#pragma unroll
      for (int j = 0; j < 8; ++j) Wl[(n0 + j) * ST + k] = v[j];
    }
  }
  __syncthreads();

  const int lane = tid & 63;
  const int quad = lane >> 4;
  const int l16 = lane & 15;
  const int w = tid >> 6;
  unsigned short* myC = &Cl[w][0];

  const int wid = blockIdx.x * 4 + w;
  const int nw = gridDim.x * 4;
  const int G = (N + 15) >> 4;
  constexpr int KT = K / 32;

  for (int g = wid; g < G; g += nw) {
    int rowA = (g << 4) + l16;
    if (rowA >= N) rowA = N - 1;
    f32x4 acc[4] = {{0.f, 0.f, 0.f, 0.f}, {0.f, 0.f, 0.f, 0.f},
                    {0.f, 0.f, 0.f, 0.f}, {0.f, 0.f, 0.f, 0.f}};
#pragma unroll
    for (int kt = 0; kt < KT; ++kt) {
      const int koff = kt * 32 + quad * 8;
      bf16x8 Af;
      if (FIRST && !isb) {
        const float* hp = (const float*)hin + (size_t)rowA * K + koff;
        const float4 u0 = *(const float4*)hp;
        const float4 u1 = *(const float4*)(hp + 4);
        Af[0] = (short)f2b(u0.x); Af[1] = (short)f2b(u0.y);
        Af[2] = (short)f2b(u0.z); Af[3] = (short)f2b(u0.w);
        Af[4] = (short)f2b(u1.x); Af[5] = (short)f2b(u1.y);
        Af[6] = (short)f2b(u1.z); Af[7] = (short)f2b(u1.w);
      } else {
        Af = *(const bf16x8*)((const unsigned short*)hin + (size_t)rowA * K + koff);
      }
#pragma unroll
      for (int nt = 0; nt < 4; ++nt) {
        const bf16x8 Bf = *(const bf16x8*)&Wl[(nt * 16 + l16) * ST + koff];
        acc[nt] = __builtin_amdgcn_mfma_f32_16x16x32_bf16(Af, Bf, acc[nt], 0, 0, 0);
      }
    }
    // epilogue: acc -> per-wave LDS tile (transpose) -> coalesced 16B stores
    const int rowD = quad * 4;
#pragma unroll
    for (int r = 0; r < 4; ++r) {
      const int nodeW = (g << 4) + rowD + r;
      const float f = (SCALE && nodeW < N) ? norm_src[nodeW] : 1.0f;
#pragma unroll
      for (int nt = 0; nt < 4; ++nt)
        myC[(rowD + r) * CST + nt * 16 + l16] = f2b(SCALE ? acc[nt][r] * f : acc[nt][r]);
    }
    const int row2 = lane >> 2;
    const int c0 = (lane & 3) * 16;
    const int node = (g << 4) + row2;
    if (node < N) {
      const u16x8 v0 = *(const u16x8*)&myC[row2 * CST + c0];
      const u16x8 v1 = *(const u16x8*)&myC[row2 * CST + c0 + 8];
      *(u16x8*)(out + (size_t)node * 64 + c0) = v0;
      *(u16x8*)(out + (size_t)node * 64 + c0 + 8) = v1;
    }
  }
}

// ---------------- MFMA aggregation (SpMM with segment-indicator A) -------------------
__device__ __forceinline__ void agg_chunk_compute(unsigned trbase, int cb32, int lo,
                                                  unsigned span, int quad, f32x4* acc) {
  const int posbase = cb32 + (quad << 2);
  const unsigned u0 = (unsigned)(posbase - lo);
  bf16x8 Af;
#pragma unroll
  for (int j = 0; j < 8; ++j) {
    const unsigned off = (j < 4) ? (unsigned)j : (unsigned)(12 + j);
    Af[j] = ((u0 + off) < span) ? (short)0x3F80 : (short)0;
  }
  s16x4 t0[4], t1[4];
#pragma unroll
  for (int nt = 0; nt < 4; ++nt) {
    const unsigned a = trbase + (unsigned)(nt * 1024);
    asm volatile("ds_read_b64_tr_b16 %0, %1" : "=v"(t0[nt]) : "v"(a) : "memory");
    asm volatile("ds_read_b64_tr_b16 %0, %1 offset:512" : "=v"(t1[nt]) : "v"(a) : "memory");
  }
  asm volatile("s_waitcnt lgkmcnt(0)" ::: "memory");
  __builtin_amdgcn_sched_barrier(0);
#pragma unroll
  for (int nt = 0; nt < 4; ++nt) {
    bf16x8 Bf;
    Bf[0] = t0[nt][0]; Bf[1] = t0[nt][1]; Bf[2] = t0[nt][2]; Bf[3] = t0[nt][3];
    Bf[4] = t1[nt][0]; Bf[5] = t1[nt][1]; Bf[6] = t1[nt][2]; Bf[7] = t1[nt][3];
    acc[nt] = __builtin_amdgcn_mfma_f32_16x16x32_bf16(Af, Bf, acc[nt], 0, 0, 0);
  }
}

template <bool LAST>
__global__ void __launch_bounds__(256) k_aggregate(
    const unsigned short* __restrict__ proj,
    const int* __restrict__ edgeSrc, const int* __restrict__ rowStart,
    const float* __restrict__ norm_dst, const float* __restrict__ norm_src,
    const void* __restrict__ bias, const int* __restrict__ flag,
    int N, int E, void* __restrict__ outp) {
  __shared__ unsigned short lds[4][2048];  // 4 KB per wave: [32 edges][64 cols]
  const bool isb = (*flag != 0);
  const int tid = threadIdx.x;
  const int w = tid >> 6;
  const int lane = tid & 63;
  const int l16 = lane & 15;
  const int quad = lane >> 4;
  const int e32 = lane & 31;  // edge slot within chunk
  const int p = lane >> 5;    // 64-byte half of the 128-byte row

  const int wid = blockIdx.x * 4 + w;
  const int g0 = wid * 8;

  float bcol[4];
#pragma unroll
  for (int nt = 0; nt < 4; ++nt) {
    const int col = nt * 16 + l16;
    bcol[nt] = isb ? b2f(((const unsigned short*)bias)[col]) : ((const float*)bias)[col];
  }

  const int cb = rowStart[min(g0, N)];
  const int ce = rowStart[min(g0 + 8, N)];
  const int L = ce - cb;
  const int nch = (L + 31) >> 5;

  const int rsi = min(g0 + min(l16, 8), N);
  const int rsj = min(g0 + min(l16 + 1, 8), N);
  const int lo = rowStart[rsi];
  const unsigned span = (unsigned)(rowStart[rsj] - lo);

  int idxc[6];
#pragma unroll
  for (int t = 0; t < 6; ++t) {
    const int pos = min(cb + t * 32 + e32, E - 1);
    idxc[t] = edgeSrc[pos];
  }

  unsigned short* myl = &lds[w][0];
  unsigned wofs[4];
#pragma unroll
  for (int q = 0; q < 4; ++q) {
    const int n0 = p * 32 + q * 8;
    wofs[q] = (unsigned)((n0 >> 4) * 512 + e32 * 16 + (n0 & 15));
  }
  const unsigned trbase = (unsigned)(uintptr_t)myl + (unsigned)lane * 8u;

  f32x4 acc[4] = {{0.f, 0.f, 0.f, 0.f}, {0.f, 0.f, 0.f, 0.f},
                  {0.f, 0.f, 0.f, 0.f}, {0.f, 0.f, 0.f, 0.f}};

  i32x4 gb[2][4];
#define AGG_ISSUE(t, b)                                                         \
  {                                                                             \
    const unsigned short* rp = proj + (size_t)idxc[t] * 64 + p * 32;            \
    gb[b][0] = *(const i32x4*)(rp);                                             \
    gb[b][1] = *(const i32x4*)(rp + 8);                                         \
    gb[b][2] = *(const i32x4*)(rp + 16);                                        \
    gb[b][3] = *(const i32x4*)(rp + 24);                                        \
  }
  if (0 < nch) AGG_ISSUE(0, 0);
  if (1 < nch) AGG_ISSUE(1, 1);

#pragma unroll
  for (int tt = 0; tt < 6; ++tt) {
    if (tt < nch) {
#pragma unroll
      for (int q = 0; q < 4; ++q) *(i32x4*)(myl + wofs[q]) = gb[tt & 1][q];
      if (tt + 2 < 6 && tt + 2 < nch) AGG_ISSUE(tt + 2, tt & 1);
      asm volatile("s_waitcnt lgkmcnt(0)" ::: "memory");
      agg_chunk_compute(trbase, cb + tt * 32, lo, span, quad, acc);
    }
  }
  for (int t = 6; t < nch; ++t) {
    const int pos = min(cb + t * 32 + e32, E - 1);
    const int idx = edgeSrc[pos];
    const unsigned short* rp = proj + (size_t)idx * 64 + p * 32;
    i32x4 g4[4];
    g4[0] = *(const i32x4*)(rp);
    g4[1] = *(const i32x4*)(rp + 8);
    g4[2] = *(const i32x4*)(rp + 16);
    g4[3] = *(const i32x4*)(rp + 24);
#pragma unroll
    for (int q = 0; q < 4; ++q) *(i32x4*)(myl + wofs[q]) = g4[q];
    asm volatile("s_waitcnt lgkmcnt(0)" ::: "memory");
    agg_chunk_compute(trbase, cb + t * 32, lo, span, quad, acc);
  }
#undef AGG_ISSUE

#pragma unroll
  for (int reg = 0; reg < 4; ++reg) {
    const int row = quad * 4 + reg;
    const int node = g0 + row;
    if (row < 8 && node < N) {
      const float nd = norm_dst[node];
      const float esc = LAST ? 1.f : norm_src[node];
#pragma unroll
      for (int nt = 0; nt < 4; ++nt) {
        float x = fmaxf(fmaf(acc[nt][reg], nd, bcol[nt]), 0.f);
        if (!LAST) x *= esc;
        const size_t o = (size_t)node * 64 + nt * 16 + l16;
        if (LAST && !isb)
          ((float*)outp)[o] = x;
        else
          ((unsigned short*)outp)[o] = f2b(x);
      }
    }
  }
}

extern "C" void kernel_launch(void* const* d_in, const int* in_sizes, int n_in,
                              void* d_out, int out_size, void* d_ws, size_t ws_size,
                              hipStream_t stream) {
  const void* features = d_in[0];
  const void* W0 = d_in[1];
  const void* b0 = d_in[2];
  const void* W1 = d_in[3];
  const void* b1 = d_in[4];
  const void* W2 = d_in[5];
  const void* b2 = d_in[6];
  const int* src = (const int*)d_in[7];
  const int* dst = (const int*)d_in[8];
  const int N = in_sizes[0] / 128;
  const int E = in_sizes[7];
  const int NBUCK = (N + 255) >> 8;
  const int M = NBUCK * 256;
  const int M2 = 2 * M;

  char* w = (char*)d_ws;
  size_t off = 0;
  auto alloc = [&](size_t bytes) {
    void* p = w + off;
    off = (off + bytes + 255) & ~(size_t)255;
    return p;
  };
  int* flag = (int*)alloc(4);
  int* rowStart = (int*)alloc((size_t)(N + 1) * 4);
  int* counts = (int*)alloc((size_t)M2 * 4);
  int* bsums = (int*)alloc(1024 * 4);
  float* norm_src = (float*)alloc((size_t)N * 4);
  float* norm_dst = (float*)alloc((size_t)N * 4);
  int* tmp = (int*)alloc((size_t)E * 4);
  unsigned char* tmp2 = (unsigned char*)alloc((size_t)E);
  int* edgeSrc = (int*)alloc((size_t)E * 4);
  unsigned short* projA = (unsigned short*)alloc((size_t)N * 64 * 2);  // bf16
  unsigned short* hB = (unsigned short*)d_out;  // inter-layer h (bf16) in d_out

  const size_t lds_nb = (size_t)NBUCK * 2 * 4;
  const int GB = 1024;  // 4096 waves: staging amortized, 4 waves/SIMD for BW

  // CSR build — zero global atomics end-to-end, no memset needed.
  k_passA<<<257, 256, lds_nb, stream>>>(src, dst, E, NBUCK, M, counts,
                                        (const unsigned short*)features, flag);
  const int NB2 = (M2 + 255) / 256;
  k_scan1<<<NB2, 256, 0, stream>>>(counts, M2, bsums);
  k_scan2<<<1, 1024, 0, stream>>>(bsums, NB2, rowStart, N, E);
  k_scan3<<<NB2, 256, 0, stream>>>(counts, M2, bsums);
  k_passC<<<256, 256, lds_nb, stream>>>(src, dst, E, NBUCK, M, counts, tmp, tmp2);
  k_passD<<<NBUCK, 256, 0, stream>>>(tmp, tmp2, counts, NBUCK, M, N, E,
                                     rowStart, edgeSrc, norm_src, norm_dst);

  const int AB = (((N + 7) / 8) + 3) / 4;  // 8 nodes/wave, 4 waves/block
  // layer 0 (ns folded into gemm0 epilogue)
  k_gemm<128, true, true><<<GB, 256, 0, stream>>>(features, W0, flag, norm_src, N, projA);
  k_aggregate<false><<<AB, 256, 0, stream>>>(projA, edgeSrc, rowStart, norm_dst, norm_src, b0, flag, N, E, hB);
  // layer 1 (h pre-scaled by ns in agg epilogue)
  k_gemm<64, false, false><<<GB, 256, 0, stream>>>(hB, W1, flag, nullptr, N, projA);
  k_aggregate<false><<<AB, 256, 0, stream>>>(projA, edgeSrc, rowStart, norm_dst, norm_src, b1, flag, N, E, hB);
  // layer 2 -> d_out
  k_gemm<64, false, false><<<GB, 256, 0, stream>>>(hB, W2, flag, nullptr, N, projA);
  k_aggregate<true><<<AB, 256, 0, stream>>>(projA, edgeSrc, rowStart, norm_dst, norm_src, b2, flag, N, E, d_out);
}